// Round 1
// baseline (178.521 us; speedup 1.0000x reference)
//
#include <hip/hip_runtime.h>

#define BINS 8
#define BLOCK 256

__global__ void init_acc_kernel(float* acc) {
    acc[0] = 0.0f;  // total
    acc[1] = 0.0f;  // npos
}

__device__ __forceinline__ float comp4(const float4& v, int i) {
    return (i == 0) ? v.x : (i == 1) ? v.y : (i == 2) ? v.z : v.w;
}

// Each thread processes 4 consecutive pixels (same batch b since HW % 4 == 0).
// All global reads are 16B vectorized.
__global__ __launch_bounds__(BLOCK) void dfl_main_kernel(
    const float* __restrict__ logits,   // [B, 32, HW]
    const float* __restrict__ targets,  // [B, HW, 4]
    const int*   __restrict__ mask,     // [B, HW]
    float* __restrict__ acc,            // acc[0]=total, acc[1]=npos
    int B, int HW) {

    const int g = blockIdx.x * BLOCK + threadIdx.x;
    const int ngroups = B * (HW >> 2);

    float tsum = 0.0f;
    float tcnt = 0.0f;

    if (g < ngroups) {
        const int p4 = g << 2;            // flattened pixel index b*HW + pp
        const int b  = p4 / HW;
        const int pp = p4 - b * HW;

        const float* base = logits + (size_t)b * 4 * BINS * HW + pp;

        // targets for the 4 pixels: each float4 = 4 coords of one pixel
        const float4* tgt = (const float4*)(targets + (size_t)p4 * 4);
        float4 t4[4];
#pragma unroll
        for (int i = 0; i < 4; ++i) t4[i] = tgt[i];

        const int4 mk = *(const int4*)(mask + p4);
        float msk[4];
        msk[0] = mk.x ? 1.0f : 0.0f;
        msk[1] = mk.y ? 1.0f : 0.0f;
        msk[2] = mk.z ? 1.0f : 0.0f;
        msk[3] = mk.w ? 1.0f : 0.0f;
        tcnt = msk[0] + msk[1] + msk[2] + msk[3];

#pragma unroll
        for (int c = 0; c < 4; ++c) {
            // load 8 bins x 4 pixels as float4s (coalesced across the wave)
            float4 xv[BINS];
#pragma unroll
            for (int j = 0; j < BINS; ++j)
                xv[j] = *(const float4*)(base + (size_t)(c * BINS + j) * HW);

#pragma unroll
            for (int i = 0; i < 4; ++i) {
                float x[BINS];
#pragma unroll
                for (int j = 0; j < BINS; ++j) x[j] = comp4(xv[j], i);

                float t = comp4(t4[i], c);
                t = fminf(fmaxf(t, 0.0f), (float)(BINS - 1) - 0.0001f);
                float lf = floorf(t);
                int   li = (int)lf;
                int   ui = li + 1;          // t <= 6.9999 -> li <= 6 -> ui <= 7
                float wu = t - lf;
                float wl = 1.0f - wu;

                // logsumexp over 8 bins
                float m = x[0];
#pragma unroll
                for (int j = 1; j < BINS; ++j) m = fmaxf(m, x[j]);
                float s = 0.0f;
#pragma unroll
                for (int j = 0; j < BINS; ++j) s += __expf(x[j] - m);
                float lse = m + __logf(s);

                // select x[li], x[ui] (unrolled cndmask chain)
                float xl = x[0], xu = x[0];
#pragma unroll
                for (int j = 1; j < BINS; ++j) {
                    xl = (li == j) ? x[j] : xl;
                    xu = (ui == j) ? x[j] : xu;
                }

                float per = lse - (wl * xl + wu * xu);
                tsum += msk[i] * per;
            }
        }
    }

    // wave64 reduction
#pragma unroll
    for (int off = 32; off > 0; off >>= 1) {
        tsum += __shfl_down(tsum, off, 64);
        tcnt += __shfl_down(tcnt, off, 64);
    }

    __shared__ float ssum[BLOCK / 64];
    __shared__ float scnt[BLOCK / 64];
    const int wid  = threadIdx.x >> 6;
    const int lane = threadIdx.x & 63;
    if (lane == 0) { ssum[wid] = tsum; scnt[wid] = tcnt; }
    __syncthreads();
    if (threadIdx.x == 0) {
        float bs = 0.0f, bc = 0.0f;
#pragma unroll
        for (int w = 0; w < BLOCK / 64; ++w) { bs += ssum[w]; bc += scnt[w]; }
        atomicAdd(&acc[0], bs);
        atomicAdd(&acc[1], bc);
    }
}

__global__ void finalize_kernel(const float* __restrict__ acc,
                                float* __restrict__ out) {
    float total = acc[0];
    float npos  = acc[1];
    float loss  = total / (fmaxf(npos, 1.0f) * 4.0f);
    out[0] = (npos > 0.0f) ? loss : 0.0f;
}

extern "C" void kernel_launch(void* const* d_in, const int* in_sizes, int n_in,
                              void* d_out, int out_size, void* d_ws, size_t ws_size,
                              hipStream_t stream) {
    const float* logits  = (const float*)d_in[0];
    const float* targets = (const float*)d_in[1];
    const int*   mask    = (const int*)d_in[2];
    float* out = (float*)d_out;
    float* acc = (float*)d_ws;

    // Shapes fixed by setup_inputs(): B=32, H=W=160
    const int B  = 32;
    const int HW = 160 * 160;

    init_acc_kernel<<<1, 1, 0, stream>>>(acc);

    const int ngroups = B * (HW / 4);               // 204800
    const int nblocks = (ngroups + BLOCK - 1) / BLOCK;  // 800
    dfl_main_kernel<<<nblocks, BLOCK, 0, stream>>>(logits, targets, mask, acc, B, HW);

    finalize_kernel<<<1, 1, 0, stream>>>(acc, out);
}